// Round 3
// baseline (185.296 us; speedup 1.0000x reference)
//
#include <hip/hip_runtime.h>
#include <cstdint>
#include <cstddef>

// ---------------------------------------------------------------------------
// x = mean_i( softmax(q_i K^T / 16) ) @ h   with q = h@Wq, k = h@Wk
//   = sum_j c_j h_j,  c_j = (1/N) sum_i exp(e_ij)/l_i,  l_i = sum_j exp(e_ij)
//
// Round 15: R14's fp16 P-spill hit inf: dataset max e > 13.86 overflowed
// fp16 at the 2^-4 shift (q.k dot-product tails are sub-exponential, not
// Gaussian). Two-layer fix: (a) accumulators init to -9.0 log2 units ->
// P' = exp(e)*2^-9, overflow now needs e > 17.33 (~8.7 sigma); denormal
// mass fraction ~1e-4 of softmax weight, harmless even if flushed.
// (b) hard fminf(.,60000) clamp on the exp2 output, applied before BOTH
// the l partial and the P pack (self-consistent: P/l preserved if it ever
// fires) -> overflow structurally impossible. The 2^-9 scale cancels
// exactly in c_j = sum_i P'_ij/(N l'_i). proj/finish unchanged (controls).
//
// ws layout: [0,4MB) q bf16 frag-major | [4MB,8MB) k frag-major |
//   [8MB,+32KB) l fp32[8192] | c fp32[8192] | [16MB,144MB) P fp16 tiles.
// P tile layout (32x32, lane-major): tile (tr,tc) at u16 offset
//   (tr*256+tc)*1024; element s = lane*16+reg maps to
//   (row = (reg&3)+8*(reg>>2)+4*(lane>>5), col = lane&31)  [C-frag layout].
// Frag-major q/k (32x32 MFMA A/B layout) per 32-row tile = 16 KB:
//   elem (i,d): tile i>>5, slot (d>>4)*64 + (i&31) + 32*((d>>3)&1), byte d&7.
// ---------------------------------------------------------------------------

#define N_ROWS 8192
#define DIM    256

typedef __bf16 bf16x8 __attribute__((ext_vector_type(8)));
typedef unsigned short u16x8 __attribute__((ext_vector_type(8)));
typedef float f32x16 __attribute__((ext_vector_type(16)));

__device__ __forceinline__ uint16_t f2bf(float f) {
    uint32_t u = __float_as_uint(f);
    uint32_t r = (u + 0x7fffu + ((u >> 16) & 1u)) >> 16;   // RTN-even
    return (uint16_t)r;
}

__device__ __forceinline__ float fexp2(float x) {
#if __has_builtin(__builtin_amdgcn_exp2f)
    return __builtin_amdgcn_exp2f(x);                      // v_exp_f32 = 2^x
#else
    return __expf(x * 0.69314718056f);
#endif
}

// pack two f32 -> one dword of 2 fp16 (low = lo, high = hi), RTNE
__device__ __forceinline__ uint32_t pk_f16(float lo, float hi) {
    union { _Float16 h[2]; uint32_t u; } v;
    v.h[0] = (_Float16)lo;
    v.h[1] = (_Float16)hi;
    return v.u;
}

// async global->LDS, 16B/lane; lds dst is wave-uniform base + lane*16
__device__ __forceinline__ void gld16(const void* gsrc, void* ldst) {
    __builtin_amdgcn_global_load_lds(
        (const __attribute__((address_space(1))) unsigned int*)gsrc,
        (__attribute__((address_space(3))) unsigned int*)ldst, 16, 0, 0);
}

// ---------------------------------------------------------------------------
// Kernel 1 (R11 verbatim): proj. Grid 1024: bid = rt*4 + ph. h staged
// coalesced to LDS (stride-260), W per-lane scalar loads, proven repack.
// Zero-inits l_arr / c_arr / out.
// ---------------------------------------------------------------------------
__global__ __launch_bounds__(256) void proj_kernel(
        const float* __restrict__ h, const float* __restrict__ Wq,
        const float* __restrict__ Wk, uint16_t* __restrict__ qf,
        uint16_t* __restrict__ kf, float* __restrict__ l_arr,
        float* __restrict__ c_arr, float* __restrict__ out) {
    __shared__ alignas(16) float hbf[32 * 260];       // 33.3 KB h stage
    __shared__ alignas(16) uint16_t rep[4][1024];     // 8 KB wave-private repack
    const int tid = threadIdx.x, lane = tid & 63, wave = tid >> 6;
    const int bid = blockIdx.x;
    const int rt = bid >> 2, ph = bid & 3;
    const int which = ph >> 1, p = ph & 1;

    if (bid < 32)       l_arr[bid * 256 + tid] = 0.0f;
    else if (bid < 64)  c_arr[(bid - 32) * 256 + tid] = 0.0f;
    else if (bid == 64) out[tid] = 0.0f;

    const float* __restrict__ W = which ? Wk : Wq;
    uint16_t* __restrict__ dst = which ? kf : qf;
    const float scale = which ? 1.0f : (0.0625f * 1.44269504089f);

    for (int i = tid; i < 2048; i += 256) {
        int r = i >> 6, c = (i & 63) * 4;
        *(float4*)&hbf[r * 260 + c] = *(const float4*)&h[(size_t)(rt * 32 + r) * DIM + c];
    }
    __syncthreads();

    bf16x8 afrag[16];
    {
        const int r = lane & 31;
#pragma unroll
        for (int a0 = 0; a0 < 16; a0++) {
            const int c0 = a0 * 16 + (lane >> 5) * 8;
            float4 f0 = *(const float4*)&hbf[r * 260 + c0];
            float4 f1 = *(const float4*)&hbf[r * 260 + c0 + 4];
            u16x8 f;
            f[0] = f2bf(f0.x); f[1] = f2bf(f0.y); f[2] = f2bf(f0.z); f[3] = f2bf(f0.w);
            f[4] = f2bf(f1.x); f[5] = f2bf(f1.y); f[6] = f2bf(f1.z); f[7] = f2bf(f1.w);
            afrag[a0] = __builtin_bit_cast(bf16x8, f);
        }
    }

    const int ctl = wave;
    const int cl = ctl * 32 + (lane & 31);
    f32x16 acc;
#pragma unroll
    for (int i = 0; i < 16; i++) acc[i] = 0.0f;
#pragma unroll
    for (int a0 = 0; a0 < 16; a0++) {
        const int kb = a0 * 16 + (lane >> 5) * 8;
        u16x8 f;
#pragma unroll
        for (int j = 0; j < 8; j++)
            f[j] = f2bf(W[(size_t)(kb + j) * DIM + p * 128 + cl]);
        acc = __builtin_amdgcn_mfma_f32_32x32x16_bf16(
            afrag[a0], __builtin_bit_cast(bf16x8, f), acc, 0, 0, 0);
    }

    {
        const int dcl = lane & 31;
        const int a0o = dcl >> 4, hi = (dcl >> 3) & 1, jj = dcl & 7;
        const int ilb = 4 * (lane >> 5);
#pragma unroll
        for (int reg = 0; reg < 16; reg++) {
            int il = ilb + (reg & 3) + 8 * (reg >> 2);
            rep[wave][(size_t)((a0o * 64) + il + 32 * hi) * 8 + jj] =
                f2bf(acc[reg] * scale);
        }
        const uint4* rv = (const uint4*)&rep[wave][0];  // wave-local RAW
        uint4* gp = (uint4*)(dst + (size_t)rt * 8192 +
                             (size_t)(p * 4 + ctl) * 1024);
        gp[lane * 2]     = rv[lane * 2];
        gp[lane * 2 + 1] = rv[lane * 2 + 1];
    }
}

// ---------------------------------------------------------------------------
// Kernel 2: single QK^T pass + fp16 P spill. 512-thread blocks, grid 256 =
// 16 rowblocks (512 rows) x 16 colchunks (512 cols), 1 block/CU, 2
// waves/SIMD. Per barrier group: 32 KB (2 k-tiles) staged async into 2x32KB
// double buffer; 8 barriers/pass. Wave: 2 rowtiles resident, 2 acc chains
// INITIALIZED TO -9.0 (uniform 2^-9 scale on P and l; cancels in P/l;
// fp16 overflow needs e > 17.33). Per sub-tile: exp2 -> clamp 60000 ->
// l partials AND fp16 pack -> 2x dwordx4 store into P.
// ---------------------------------------------------------------------------
__global__ __launch_bounds__(512, 2) void qk_store(
        const uint16_t* __restrict__ qf, const uint16_t* __restrict__ kf,
        uint16_t* __restrict__ Pm, float* __restrict__ l_arr) {
    __shared__ alignas(16) uint16_t ktile[2][16384];  // 2 x 32 KB (2 tiles each)
    const int tid = threadIdx.x, lane = tid & 63, wave = tid >> 6;  // wave 0..7
    const int bid = blockIdx.x;
    const int cc = bid & 15, rb = bid >> 4;           // rb 0..15
    const int t0 = rb * 16 + wave * 2;                // wave's rowtiles t0, t0+1
    const int row0 = t0 * 32;

    // resident q: 2 rowtiles x 16 K-chunks = 128 regs
    const uint4* qp = (const uint4*)qf;
    bf16x8 q0[16], q1[16];
#pragma unroll
    for (int a0 = 0; a0 < 16; a0++) {
        q0[a0] = __builtin_bit_cast(bf16x8, qp[(size_t)t0 * 1024 + a0 * 64 + lane]);
        q1[a0] = __builtin_bit_cast(bf16x8, qp[(size_t)(t0 + 1) * 1024 + a0 * 64 + lane]);
    }

    float rs0[16], rs1[16];   // l partials (scaled by 2^-9)
#pragma unroll
    for (int r = 0; r < 16; r++) { rs0[r] = 0.0f; rs1[r] = 0.0f; }

    // P store base: tile (t0, cc*16) + this lane's 32B slot (lane-major)
    uint4* pst0 = (uint4*)(Pm + ((size_t)t0 * 256 + cc * 16) * 1024) + (size_t)lane * 2;
    uint4* pst1 = pst0 + 256 * 128;                   // rowtile t0+1

    const char* ksrc = (const char*)kf + (size_t)cc * 16 * 16384;  // 16 tiles

    {   // prologue: stage tiles 0,1 (32 KB) -> buffer 0; each wave 4 KB
        const char* s0 = ksrc + wave * 4096 + lane * 16;
        char* d0 = (char*)&ktile[0][0] + wave * 4096;
#pragma unroll
        for (int it = 0; it < 4; it++) gld16(s0 + it * 1024, d0 + it * 1024);
    }

    for (int g = 0; g < 8; g++) {
        __syncthreads();          // vmcnt drained: group g staged; other
                                  // buffer's readers all done
        if (g < 7) {              // prefetch group g+1 (tiles 2g+2, 2g+3)
            const char* sn = ksrc + (size_t)(2 * g + 2) * 16384 + wave * 4096 + lane * 16;
            char* dn = (char*)&ktile[(g + 1) & 1][0] + wave * 4096;
#pragma unroll
            for (int it = 0; it < 4; it++) gld16(sn + it * 1024, dn + it * 1024);
        }

#pragma unroll
        for (int sub = 0; sub < 2; sub++) {
            const int t = 2 * g + sub;
            const uint16_t* kt = &ktile[g & 1][sub * 8192];
            f32x16 acc0, acc1;    // 2 independent chains (one per rowtile)
            // init -9.0 (log2 units): exp2(acc) = exp(e) * 2^-9; fp16-safe
            // to e <= 17.33 (~8.7 sigma); scale cancels in P/l.
#pragma unroll
            for (int i = 0; i < 16; i++) { acc0[i] = -9.0f; acc1[i] = -9.0f; }
#pragma unroll
            for (int a0 = 0; a0 < 16; a0++) {
                bf16x8 b = __builtin_bit_cast(bf16x8,
                    *(const u16x8*)&kt[(size_t)(a0 * 64 + lane) * 8]);
                acc0 = __builtin_amdgcn_mfma_f32_32x32x16_bf16(q0[a0], b, acc0, 0, 0, 0);
                acc1 = __builtin_amdgcn_mfma_f32_32x32x16_bf16(q1[a0], b, acc1, 0, 0, 0);
            }

            // exp2 -> clamp -> l partials + fp16 pack + P store
            // (clamp BEFORE both l and P: self-consistent, overflow-proof)
            {
                uint4 pw; float ea, eb;
#define EPK(ACC, RS, J0, M)                                              \
                ea = fminf(fexp2(ACC[J0]), 60000.0f);                    \
                eb = fminf(fexp2(ACC[(J0) + 1]), 60000.0f);              \
                RS[J0] += ea; RS[(J0) + 1] += eb;                        \
                pw.M = pk_f16(ea, eb);
                EPK(acc0, rs0, 0, x) EPK(acc0, rs0, 2, y)
                EPK(acc0, rs0, 4, z) EPK(acc0, rs0, 6, w)
                pst0[t * 128] = pw;
                EPK(acc0, rs0, 8, x) EPK(acc0, rs0, 10, y)
                EPK(acc0, rs0, 12, z) EPK(acc0, rs0, 14, w)
                pst0[t * 128 + 1] = pw;
                EPK(acc1, rs1, 0, x) EPK(acc1, rs1, 2, y)
                EPK(acc1, rs1, 4, z) EPK(acc1, rs1, 6, w)
                pst1[t * 128] = pw;
                EPK(acc1, rs1, 8, x) EPK(acc1, rs1, 10, y)
                EPK(acc1, rs1, 12, z) EPK(acc1, rs1, 14, w)
                pst1[t * 128 + 1] = pw;
#undef EPK
            }
        }
    }

    // l reduction (scaled l; scale cancels against scaled P in colreduce)
#pragma unroll
    for (int r = 0; r < 16; r++) {
        float v0 = rs0[r], v1 = rs1[r];
        v0 += __shfl_xor(v0, 1);  v0 += __shfl_xor(v0, 2);
        v0 += __shfl_xor(v0, 4);  v0 += __shfl_xor(v0, 8);
        v0 += __shfl_xor(v0, 16);
        v1 += __shfl_xor(v1, 1);  v1 += __shfl_xor(v1, 2);
        v1 += __shfl_xor(v1, 4);  v1 += __shfl_xor(v1, 8);
        v1 += __shfl_xor(v1, 16);
        if ((lane & 31) == 0) {
            int ro = (r & 3) + 8 * (r >> 2) + 4 * (lane >> 5);
            atomicAdd(&l_arr[row0 + ro], v0);
            atomicAdd(&l_arr[row0 + 32 + ro], v1);
        }
    }
}

// ---------------------------------------------------------------------------
// Kernel 3: c_j = sum_i w_i P_ij, w_i = 1/(N l_i) (scales cancel).
// Streaming, memory-bound. Grid 1024 = 16 colchunks x 64 rowgroups (128
// rows); 512 thr. Wave owns coltiles {2w,2w+1}; per (t,ct) the wave reads
// one 2KB tile fully coalesced (lane -> uint4 lane, lane+64). Each thread:
// fixed col = lane>>1, 16 rows (parity pattern), 2 col-accs; parity fold
// via shfl_xor(1), 2 global atomics per even lane.
// ---------------------------------------------------------------------------
__global__ __launch_bounds__(512) void colreduce_kernel(
        const uint16_t* __restrict__ Pm, const float* __restrict__ l_arr,
        float* __restrict__ c_arr) {
    __shared__ float wlds[128];
    const int tid = threadIdx.x, lane = tid & 63, wave = tid >> 6;
    const int bid = blockIdx.x;
    const int cc = bid & 15, rg = bid >> 4;           // rg 0..63 (128 rows)
    if (tid < 128) wlds[tid] = 1.0f / (8192.0f * l_arr[rg * 128 + tid]);
    __syncthreads();

    const int rbase = 16 * (lane & 1);                // parity row base
    float acc0 = 0.0f, acc1 = 0.0f;
#pragma unroll
    for (int t = 0; t < 4; t++) {
        float wA[8], wB[8];
#pragma unroll
        for (int j = 0; j < 8; j++) {
            const int r = (j & 3) + 8 * (j >> 2) + rbase;
            wA[j] = wlds[t * 32 + r];                 // broadcast reads (free)
            wB[j] = wlds[t * 32 + r + 4];
        }
        const size_t trow = (size_t)(rg * 4 + t) * 256;
#pragma unroll
        for (int c = 0; c < 2; c++) {
            const uint4* up = (const uint4*)(Pm + (trow + cc * 16 + wave * 2 + c) * 1024);
            uint4 v0 = up[lane];
            uint4 v1 = up[lane + 64];
            uint32_t a[4] = {v0.x, v0.y, v0.z, v0.w};
            uint32_t b[4] = {v1.x, v1.y, v1.z, v1.w};
            float s = 0.0f;
#pragma unroll
            for (int j = 0; j < 4; j++) {
                union { uint32_t u; _Float16 h[2]; } ta, tb;
                ta.u = a[j]; tb.u = b[j];
                s += (float)ta.h[0] * wA[2 * j]
                   + (float)ta.h[1] * wA[2 * j + 1]
                   + (float)tb.h[0] * wB[2 * j]
                   + (float)tb.h[1] * wB[2 * j + 1];
            }
            if (c == 0) acc0 += s; else acc1 += s;
        }
    }

    acc0 += __shfl_xor(acc0, 1);                      // fold parities (same col)
    acc1 += __shfl_xor(acc1, 1);
    if ((lane & 1) == 0) {
        const int col = lane >> 1;                    // 0..31
        atomicAdd(&c_arr[cc * 512 + (wave * 2 + 0) * 32 + col], acc0);
        atomicAdd(&c_arr[cc * 512 + (wave * 2 + 1) * 32 + col], acc1);
    }
}

// ---------------------------------------------------------------------------
// Kernel 4 (R8 verbatim): x = c @ h. 256 blocks x 32 rows, fully unrolled.
// ---------------------------------------------------------------------------
__global__ __launch_bounds__(256) void finish_kernel(
        const float* __restrict__ h, const float* __restrict__ c_arr,
        float* __restrict__ out) {
    const int d = threadIdx.x;
    const int j0 = blockIdx.x * 32;
    float acc = 0.0f;
#pragma unroll
    for (int jj = 0; jj < 32; jj++)
        acc += c_arr[j0 + jj] * h[(size_t)(j0 + jj) * DIM + d];
    atomicAdd(&out[d], acc);
}

// ---------------------------------------------------------------------------
extern "C" void kernel_launch(void* const* d_in, const int* in_sizes, int n_in,
                              void* d_out, int out_size, void* d_ws, size_t ws_size,
                              hipStream_t stream) {
    const float* h  = (const float*)d_in[0];
    const float* Wq = (const float*)d_in[1];
    const float* Wk = (const float*)d_in[2];

    uint16_t* qf = (uint16_t*)d_ws;
    uint16_t* kf = qf + (size_t)N_ROWS * DIM;                  // +4 MB
    float* l_arr = (float*)((char*)d_ws + (size_t)8 * 1024 * 1024);
    float* c_arr = l_arr + N_ROWS;
    uint16_t* Pm = (uint16_t*)((char*)d_ws + (size_t)16 * 1024 * 1024); // 128 MiB
    float* out = (float*)d_out;

    proj_kernel<<<1024, 256, 0, stream>>>(h, Wq, Wk, qf, kf, l_arr, c_arr, out);
    qk_store<<<256, 512, 0, stream>>>(qf, kf, Pm, l_arr);
    colreduce_kernel<<<1024, 512, 0, stream>>>(Pm, l_arr, c_arr);
    finish_kernel<<<256, 256, 0, stream>>>(h, c_arr, out);
}

// Round 4
// 168.285 us; speedup vs baseline: 1.1011x; 1.1011x over previous
//
#include <hip/hip_runtime.h>
#include <cstdint>
#include <cstddef>

// ---------------------------------------------------------------------------
// x = mean_i( softmax(q_i K^T / 16) ) @ h   with q = h@Wq, k = h@Wk
//   = sum_j c_j h_j,  c_j = (1/N) sum_i exp(e_ij)/l_i,  l_i = sum_j exp(e_ij)
//
// Round 16: R15 passed (fp16 P + 2^-9 shift numerics clean) but qk_store
// ran 85us at MfmaUtil 16% / VALUBusy 14%: (a) __syncthreads per group =
// s_waitcnt vmcnt(0) drains the 8 P-stores at every barrier with only 2
// waves/SIMD to hide ~900cy store latency; (b) stores had 32B inter-lane
// stride (pst[lane*2], [lane*2+1]) -> half-line coverage per instruction
// -> L2 write-allocate RMW: FETCH 82MiB (inputs are 8), WRITE 196MiB (P is
// 128). Fix: (1) P-tile layout re-defined as uint4 idx = half*64 + lane so
// each store is one contiguous 1024B burst; (2) counted-vmcnt barrier
// (s_waitcnt vmcnt(8) + raw s_barrier): issue order [4 gld_lds, 8 stores]
// per group, vmcnt(8) retires the staging loads while stores drain under
// the next group's 64 MFMAs (T3/T4 pattern). colreduce remapped to the new
// layout (fold via shfl_xor 32). proj/finish unchanged (controls).
//
// ws layout: [0,4MB) q bf16 frag-major | [4MB,8MB) k frag-major |
//   [8MB,+32KB) l fp32[8192] | c fp32[8192] | [16MB,144MB) P fp16 tiles.
// P tile (32x32 fp16, 2KB = 128 uint4) at (tr,tc): base uint4 off
//   (tr*256+tc)*128. uint4 idx = half*64 + lane, half0 = regs 0-7, half1 =
//   regs 8-15 of MFMA C-frag lane `lane`: elem (reg r, lane L) -> row =
//   (r&3)+8*(r>>2)+4*(L>>5)  (+16 for half1 handled via r), col = L&31.
// Frag-major q/k (32x32 MFMA A/B layout) per 32-row tile = 16 KB:
//   elem (i,d): tile i>>5, slot (d>>4)*64 + (i&31) + 32*((d>>3)&1), byte d&7.
// ---------------------------------------------------------------------------

#define N_ROWS 8192
#define DIM    256

typedef __bf16 bf16x8 __attribute__((ext_vector_type(8)));
typedef unsigned short u16x8 __attribute__((ext_vector_type(8)));
typedef float f32x16 __attribute__((ext_vector_type(16)));

__device__ __forceinline__ uint16_t f2bf(float f) {
    uint32_t u = __float_as_uint(f);
    uint32_t r = (u + 0x7fffu + ((u >> 16) & 1u)) >> 16;   // RTN-even
    return (uint16_t)r;
}

__device__ __forceinline__ float fexp2(float x) {
#if __has_builtin(__builtin_amdgcn_exp2f)
    return __builtin_amdgcn_exp2f(x);                      // v_exp_f32 = 2^x
#else
    return __expf(x * 0.69314718056f);
#endif
}

// pack two f32 -> one dword of 2 fp16 (low = lo, high = hi), RTNE
__device__ __forceinline__ uint32_t pk_f16(float lo, float hi) {
    union { _Float16 h[2]; uint32_t u; } v;
    v.h[0] = (_Float16)lo;
    v.h[1] = (_Float16)hi;
    return v.u;
}

// async global->LDS, 16B/lane; lds dst is wave-uniform base + lane*16
__device__ __forceinline__ void gld16(const void* gsrc, void* ldst) {
    __builtin_amdgcn_global_load_lds(
        (const __attribute__((address_space(1))) unsigned int*)gsrc,
        (__attribute__((address_space(3))) unsigned int*)ldst, 16, 0, 0);
}

// ---------------------------------------------------------------------------
// Kernel 1 (R11 verbatim): proj. Grid 1024: bid = rt*4 + ph. h staged
// coalesced to LDS (stride-260), W per-lane scalar loads, proven repack.
// Zero-inits l_arr / c_arr / out.
// ---------------------------------------------------------------------------
__global__ __launch_bounds__(256) void proj_kernel(
        const float* __restrict__ h, const float* __restrict__ Wq,
        const float* __restrict__ Wk, uint16_t* __restrict__ qf,
        uint16_t* __restrict__ kf, float* __restrict__ l_arr,
        float* __restrict__ c_arr, float* __restrict__ out) {
    __shared__ alignas(16) float hbf[32 * 260];       // 33.3 KB h stage
    __shared__ alignas(16) uint16_t rep[4][1024];     // 8 KB wave-private repack
    const int tid = threadIdx.x, lane = tid & 63, wave = tid >> 6;
    const int bid = blockIdx.x;
    const int rt = bid >> 2, ph = bid & 3;
    const int which = ph >> 1, p = ph & 1;

    if (bid < 32)       l_arr[bid * 256 + tid] = 0.0f;
    else if (bid < 64)  c_arr[(bid - 32) * 256 + tid] = 0.0f;
    else if (bid == 64) out[tid] = 0.0f;

    const float* __restrict__ W = which ? Wk : Wq;
    uint16_t* __restrict__ dst = which ? kf : qf;
    const float scale = which ? 1.0f : (0.0625f * 1.44269504089f);

    for (int i = tid; i < 2048; i += 256) {
        int r = i >> 6, c = (i & 63) * 4;
        *(float4*)&hbf[r * 260 + c] = *(const float4*)&h[(size_t)(rt * 32 + r) * DIM + c];
    }
    __syncthreads();

    bf16x8 afrag[16];
    {
        const int r = lane & 31;
#pragma unroll
        for (int a0 = 0; a0 < 16; a0++) {
            const int c0 = a0 * 16 + (lane >> 5) * 8;
            float4 f0 = *(const float4*)&hbf[r * 260 + c0];
            float4 f1 = *(const float4*)&hbf[r * 260 + c0 + 4];
            u16x8 f;
            f[0] = f2bf(f0.x); f[1] = f2bf(f0.y); f[2] = f2bf(f0.z); f[3] = f2bf(f0.w);
            f[4] = f2bf(f1.x); f[5] = f2bf(f1.y); f[6] = f2bf(f1.z); f[7] = f2bf(f1.w);
            afrag[a0] = __builtin_bit_cast(bf16x8, f);
        }
    }

    const int ctl = wave;
    const int cl = ctl * 32 + (lane & 31);
    f32x16 acc;
#pragma unroll
    for (int i = 0; i < 16; i++) acc[i] = 0.0f;
#pragma unroll
    for (int a0 = 0; a0 < 16; a0++) {
        const int kb = a0 * 16 + (lane >> 5) * 8;
        u16x8 f;
#pragma unroll
        for (int j = 0; j < 8; j++)
            f[j] = f2bf(W[(size_t)(kb + j) * DIM + p * 128 + cl]);
        acc = __builtin_amdgcn_mfma_f32_32x32x16_bf16(
            afrag[a0], __builtin_bit_cast(bf16x8, f), acc, 0, 0, 0);
    }

    {
        const int dcl = lane & 31;
        const int a0o = dcl >> 4, hi = (dcl >> 3) & 1, jj = dcl & 7;
        const int ilb = 4 * (lane >> 5);
#pragma unroll
        for (int reg = 0; reg < 16; reg++) {
            int il = ilb + (reg & 3) + 8 * (reg >> 2);
            rep[wave][(size_t)((a0o * 64) + il + 32 * hi) * 8 + jj] =
                f2bf(acc[reg] * scale);
        }
        const uint4* rv = (const uint4*)&rep[wave][0];  // wave-local RAW
        uint4* gp = (uint4*)(dst + (size_t)rt * 8192 +
                             (size_t)(p * 4 + ctl) * 1024);
        gp[lane * 2]     = rv[lane * 2];
        gp[lane * 2 + 1] = rv[lane * 2 + 1];
    }
}

// ---------------------------------------------------------------------------
// Kernel 2: single QK^T pass + fp16 P spill. 512-thread blocks, grid 256 =
// 16 rowblocks (512 rows) x 16 colchunks (512 cols), 1 block/CU, 2
// waves/SIMD. Per group: 32 KB (2 k-tiles) staged async into 2x32KB double
// buffer. Counted-vmcnt barriers (vmcnt(8) + raw s_barrier) let the 8
// P-stores/group drain under the next group's MFMAs. Acc chains init to
// -9.0 (2^-9 scale, cancels in P/l; fp16-safe to e<=17.33); exp2 -> clamp
// 60000 -> l partials + fp16 pack -> 4x contiguous 1024B stores.
// ---------------------------------------------------------------------------
__global__ __launch_bounds__(512, 2) void qk_store(
        const uint16_t* __restrict__ qf, const uint16_t* __restrict__ kf,
        uint16_t* __restrict__ Pm, float* __restrict__ l_arr) {
    __shared__ alignas(16) uint16_t ktile[2][16384];  // 2 x 32 KB (2 tiles each)
    const int tid = threadIdx.x, lane = tid & 63, wave = tid >> 6;  // wave 0..7
    const int bid = blockIdx.x;
    const int cc = bid & 15, rb = bid >> 4;           // rb 0..15
    const int t0 = rb * 16 + wave * 2;                // wave's rowtiles t0, t0+1
    const int row0 = t0 * 32;

    // resident q: 2 rowtiles x 16 K-chunks = 128 regs
    const uint4* qp = (const uint4*)qf;
    bf16x8 q0[16], q1[16];
#pragma unroll
    for (int a0 = 0; a0 < 16; a0++) {
        q0[a0] = __builtin_bit_cast(bf16x8, qp[(size_t)t0 * 1024 + a0 * 64 + lane]);
        q1[a0] = __builtin_bit_cast(bf16x8, qp[(size_t)(t0 + 1) * 1024 + a0 * 64 + lane]);
    }

    float rs0[16], rs1[16];   // l partials (scaled by 2^-9)
#pragma unroll
    for (int r = 0; r < 16; r++) { rs0[r] = 0.0f; rs1[r] = 0.0f; }

    // P store bases: tile (t0, cc*16); uint4 idx = half*64 + lane per tile
    uint4* pb0 = (uint4*)Pm + ((size_t)t0 * 256 + cc * 16) * 128 + lane;
    uint4* pb1 = pb0 + 256 * 128;                     // rowtile t0+1

    const char* ksrc = (const char*)kf + (size_t)cc * 16 * 16384;  // 16 tiles

    {   // prologue: stage tiles 0,1 (32 KB) -> buffer 0; each wave 4 KB
        const char* s0 = ksrc + wave * 4096 + lane * 16;
        char* d0 = (char*)&ktile[0][0] + wave * 4096;
#pragma unroll
        for (int it = 0; it < 4; it++) gld16(s0 + it * 1024, d0 + it * 1024);
    }
    asm volatile("s_waitcnt vmcnt(0)" ::: "memory");
    __builtin_amdgcn_s_barrier();

    for (int g = 0; g < 8; g++) {
        if (g > 0) {
            // issue order last group: [4 gld_lds, 8 stores]; vmcnt(8)
            // retires the staging loads (oldest), stores keep draining
            asm volatile("s_waitcnt vmcnt(8)" ::: "memory");
            __builtin_amdgcn_s_barrier();
        }
        if (g < 7) {              // prefetch group g+1 (tiles 2g+2, 2g+3)
            const char* sn = ksrc + (size_t)(2 * g + 2) * 16384 + wave * 4096 + lane * 16;
            char* dn = (char*)&ktile[(g + 1) & 1][0] + wave * 4096;
#pragma unroll
            for (int it = 0; it < 4; it++) gld16(sn + it * 1024, dn + it * 1024);
        }

#pragma unroll
        for (int sub = 0; sub < 2; sub++) {
            const int t = 2 * g + sub;
            const uint16_t* kt = &ktile[g & 1][sub * 8192];
            f32x16 acc0, acc1;    // 2 independent chains (one per rowtile)
            // init -9.0 (log2 units): exp2(acc) = exp(e) * 2^-9; fp16-safe
            // to e <= 17.33 (~8.7 sigma); scale cancels in P/l.
#pragma unroll
            for (int i = 0; i < 16; i++) { acc0[i] = -9.0f; acc1[i] = -9.0f; }
#pragma unroll
            for (int a0 = 0; a0 < 16; a0++) {
                bf16x8 b = __builtin_bit_cast(bf16x8,
                    *(const u16x8*)&kt[(size_t)(a0 * 64 + lane) * 8]);
                acc0 = __builtin_amdgcn_mfma_f32_32x32x16_bf16(q0[a0], b, acc0, 0, 0, 0);
                acc1 = __builtin_amdgcn_mfma_f32_32x32x16_bf16(q1[a0], b, acc1, 0, 0, 0);
            }

            // exp2 -> clamp -> l partials + fp16 pack + 4 contiguous stores
            // (clamp BEFORE both l and P: self-consistent, overflow-proof)
            {
                uint4 pw; float ea, eb;
#define EPK(ACC, RS, J0, M)                                              \
                ea = fminf(fexp2(ACC[J0]), 60000.0f);                    \
                eb = fminf(fexp2(ACC[(J0) + 1]), 60000.0f);              \
                RS[J0] += ea; RS[(J0) + 1] += eb;                        \
                pw.M = pk_f16(ea, eb);
                EPK(acc0, rs0, 0, x) EPK(acc0, rs0, 2, y)
                EPK(acc0, rs0, 4, z) EPK(acc0, rs0, 6, w)
                pb0[t * 128] = pw;                    // half 0 (regs 0-7)
                EPK(acc0, rs0, 8, x) EPK(acc0, rs0, 10, y)
                EPK(acc0, rs0, 12, z) EPK(acc0, rs0, 14, w)
                pb0[t * 128 + 64] = pw;               // half 1 (regs 8-15)
                EPK(acc1, rs1, 0, x) EPK(acc1, rs1, 2, y)
                EPK(acc1, rs1, 4, z) EPK(acc1, rs1, 6, w)
                pb1[t * 128] = pw;
                EPK(acc1, rs1, 8, x) EPK(acc1, rs1, 10, y)
                EPK(acc1, rs1, 12, z) EPK(acc1, rs1, 14, w)
                pb1[t * 128 + 64] = pw;
#undef EPK
            }
        }
    }

    // l reduction (scaled l; scale cancels against scaled P in colreduce)
#pragma unroll
    for (int r = 0; r < 16; r++) {
        float v0 = rs0[r], v1 = rs1[r];
        v0 += __shfl_xor(v0, 1);  v0 += __shfl_xor(v0, 2);
        v0 += __shfl_xor(v0, 4);  v0 += __shfl_xor(v0, 8);
        v0 += __shfl_xor(v0, 16);
        v1 += __shfl_xor(v1, 1);  v1 += __shfl_xor(v1, 2);
        v1 += __shfl_xor(v1, 4);  v1 += __shfl_xor(v1, 8);
        v1 += __shfl_xor(v1, 16);
        if ((lane & 31) == 0) {
            int ro = (r & 3) + 8 * (r >> 2) + 4 * (lane >> 5);
            atomicAdd(&l_arr[row0 + ro], v0);
            atomicAdd(&l_arr[row0 + 32 + ro], v1);
        }
    }
}

// ---------------------------------------------------------------------------
// Kernel 3: c_j = sum_i w_i P_ij, w_i = 1/(N l_i) (scales cancel).
// Streaming, memory-bound. Grid 1024 = 16 colchunks x 64 rowgroups (128
// rows); 512 thr. Wave owns coltiles {2w,2w+1}; per (t,c) the wave reads
// one 2KB tile as two contiguous 1024B bursts (up[lane] = regs0-7 of
// P-lane `lane`, up[lane+64] = regs8-15). Thread col = lane&31; lanes
// (lane, lane^32) cover disjoint row sets, folded via shfl_xor(32).
// ---------------------------------------------------------------------------
__global__ __launch_bounds__(512) void colreduce_kernel(
        const uint16_t* __restrict__ Pm, const float* __restrict__ l_arr,
        float* __restrict__ c_arr) {
    __shared__ float wlds[128];
    const int tid = threadIdx.x, lane = tid & 63, wave = tid >> 6;
    const int bid = blockIdx.x;
    const int cc = bid & 15, rg = bid >> 4;           // rg 0..63 (128 rows)
    if (tid < 128) wlds[tid] = 1.0f / (8192.0f * l_arr[rg * 128 + tid]);
    __syncthreads();

    const int rb4 = 4 * (lane >> 5);                  // half-wave row offset
    float acc0 = 0.0f, acc1 = 0.0f;
#pragma unroll
    for (int t = 0; t < 4; t++) {
        float wA[8], wB[8];
#pragma unroll
        for (int j = 0; j < 8; j++) {
            const int r = (j & 3) + 8 * (j >> 2) + rb4;  // {0-3,8-11}+rb4
            wA[j] = wlds[t * 32 + r];                 // broadcast reads (free)
            wB[j] = wlds[t * 32 + r + 16];
        }
        const size_t trow = (size_t)(rg * 4 + t) * 256;
#pragma unroll
        for (int c = 0; c < 2; c++) {
            const uint4* up = (const uint4*)(Pm + (trow + cc * 16 + wave * 2 + c) * 1024);
            uint4 v0 = up[lane];                      // regs 0-7
            uint4 v1 = up[lane + 64];                 // regs 8-15
            uint32_t a[4] = {v0.x, v0.y, v0.z, v0.w};
            uint32_t b[4] = {v1.x, v1.y, v1.z, v1.w};
            float s = 0.0f;
#pragma unroll
            for (int j = 0; j < 4; j++) {
                union { uint32_t u; _Float16 h[2]; } ta, tb;
                ta.u = a[j]; tb.u = b[j];
                s += (float)ta.h[0] * wA[2 * j]
                   + (float)ta.h[1] * wA[2 * j + 1]
                   + (float)tb.h[0] * wB[2 * j]
                   + (float)tb.h[1] * wB[2 * j + 1];
            }
            if (c == 0) acc0 += s; else acc1 += s;
        }
    }

    acc0 += __shfl_xor(acc0, 32);                     // fold half-wave rows
    acc1 += __shfl_xor(acc1, 32);
    if (lane < 32) {                                  // col = lane
        atomicAdd(&c_arr[cc * 512 + (wave * 2 + 0) * 32 + lane], acc0);
        atomicAdd(&c_arr[cc * 512 + (wave * 2 + 1) * 32 + lane], acc1);
    }
}

// ---------------------------------------------------------------------------
// Kernel 4 (R8 verbatim): x = c @ h. 256 blocks x 32 rows, fully unrolled.
// ---------------------------------------------------------------------------
__global__ __launch_bounds__(256) void finish_kernel(
        const float* __restrict__ h, const float* __restrict__ c_arr,
        float* __restrict__ out) {
    const int d = threadIdx.x;
    const int j0 = blockIdx.x * 32;
    float acc = 0.0f;
#pragma unroll
    for (int jj = 0; jj < 32; jj++)
        acc += c_arr[j0 + jj] * h[(size_t)(j0 + jj) * DIM + d];
    atomicAdd(&out[d], acc);
}

// ---------------------------------------------------------------------------
extern "C" void kernel_launch(void* const* d_in, const int* in_sizes, int n_in,
                              void* d_out, int out_size, void* d_ws, size_t ws_size,
                              hipStream_t stream) {
    const float* h  = (const float*)d_in[0];
    const float* Wq = (const float*)d_in[1];
    const float* Wk = (const float*)d_in[2];

    uint16_t* qf = (uint16_t*)d_ws;
    uint16_t* kf = qf + (size_t)N_ROWS * DIM;                  // +4 MB
    float* l_arr = (float*)((char*)d_ws + (size_t)8 * 1024 * 1024);
    float* c_arr = l_arr + N_ROWS;
    uint16_t* Pm = (uint16_t*)((char*)d_ws + (size_t)16 * 1024 * 1024); // 128 MiB
    float* out = (float*)d_out;

    proj_kernel<<<1024, 256, 0, stream>>>(h, Wq, Wk, qf, kf, l_arr, c_arr, out);
    qk_store<<<256, 512, 0, stream>>>(qf, kf, Pm, l_arr);
    colreduce_kernel<<<1024, 512, 0, stream>>>(Pm, l_arr, c_arr);
    finish_kernel<<<256, 256, 0, stream>>>(h, c_arr, out);
}